// Round 26
// baseline (129.090 us; speedup 1.0000x reference)
//
#include <hip/hip_runtime.h>

#define HW   (256*256)        // 65536
#define VOL  (64*HW)          // 4194304 per batch volume
#define NTOT (4ull*VOL)
#define C1v  1e-4f
#define C2v  9e-4f
#define EPSv 1e-8f

typedef float    f2 __attribute__((ext_vector_type(2)));
typedef float    f4 __attribute__((ext_vector_type(4)));
typedef _Float16 h2 __attribute__((ext_vector_type(2)));
typedef _Float16 h4 __attribute__((ext_vector_type(4)));
typedef _Float16 h8 __attribute__((ext_vector_type(8)));

// ws layout:
// [0      .. 63]       : w[11] float (1D separable weights)
// [64     .. 131135]   : partials[16384] double
// [131136 .. ]         : D-blurred fields for ONE batch (reused across batches),
//                        FA = h4{X, Y, S=x2+y2, P=xy}[VOL]  (33.5 MB)

__global__ void init_weights(const float* __restrict__ k3, float* __restrict__ w) {
    int i = threadIdx.x;
    if (i < 11) {
        float s = 0.f;
        for (int t = 0; t < 121; ++t) s += k3[i * 121 + t];
        w[i] = s;   // k3 is separable: row-sum = 1D weight
    }
}

// Pass 1 (per batch): D-conv of {x, y, x2+y2, xy} via scalar fp32 register
// rings (r19-proven config: halves, d0 = blockIdx.y*32, cndmask zeroing).
// grid: (256, 2) x 256.
__global__ __launch_bounds__(256) void dblur(
    const float* __restrict__ x, const float* __restrict__ y,
    const float* __restrict__ w11, char* __restrict__ fields, int b)
{
    const int col = blockIdx.x * 256 + threadIdx.x;  // 0..65535 within slice
    const int d0  = blockIdx.y * 32;                 // runtime, wave-uniform

    float wl[11];
#pragma unroll
    for (int t = 0; t < 11; ++t) wl[t] = w11[t];

    const float* xb = x + (size_t)b * VOL;
    const float* yb = y + (size_t)b * VOL;
    h4* FA = (h4*)fields;

    float bX[11], bY[11], bS[11], bP[11];
#pragma unroll
    for (int t = 0; t < 11; ++t) { bX[t] = 0; bY[t] = 0; bS[t] = 0; bP[t] = 0; }

#pragma unroll
    for (int s = 0; s < 42; ++s) {
        const int slot = s % 11;                    // compile-time
        int dd  = d0 - 5 + s;                       // runtime, uniform
        int ddc = min(max(dd, 0), 63);              // clamped (always-valid addr)
        bool ok = (dd >= 0) & (dd < 64);
        size_t idx = (size_t)ddc * HW + col;
        float xv = xb[idx];
        float yv = yb[idx];
        if (!ok) { xv = 0.f; yv = 0.f; }            // cndmask, no branch
        bX[slot] = xv;
        bY[slot] = yv;
        bS[slot] = xv * xv + yv * yv;
        bP[slot] = xv * yv;

        if (s >= 10) {                              // compile-time; emit d0 + s - 10
            float mX = 0, mY = 0, mS = 0, mP = 0;
#pragma unroll
            for (int t = 0; t < 11; ++t) {
                const int j = (s + 1 + t) % 11;     // compile-time
                float wt = wl[t];
                mX += wt * bX[j];
                mY += wt * bY[j];
                mS += wt * bS[j];
                mP += wt * bP[j];
            }
            size_t oi = (size_t)(d0 + s - 10) * HW + col;
            FA[oi] = (h4){(_Float16)mX, (_Float16)mY,
                          (_Float16)mS, (_Float16)mP};
        }
    }
}

// Pass 2 (per batch): HW-conv via MFMA banded matmuls + fused SSIM +
// reduction, with bijective XCD work-swizzle (contiguous d-slices per XCD).
// Runs immediately after its batch's dblur -> fields are L3/L2-resident.
//   PB[4][32][88]; TT aliases PB, swizzle (col&7)<<4; WB/AH[16][40].
// grid: (4, 16, 64) x 256.
__global__ __launch_bounds__(256) void hw_ssim(
    const char* __restrict__ fields, const float* __restrict__ w11,
    double* __restrict__ partials, int b)
{
    __shared__ alignas(16) _Float16 PB[4 * 32 * 88];  // 22,528 B; TT (16,384 B) aliases
    __shared__ alignas(16) _Float16 WB[16][40];       //  1,280 B
    __shared__ alignas(16) _Float16 AH[16][40];       //  1,280 B
    __shared__ float wsum[4];

    // ---- bijective XCD swizzle: nwg = 4096, divisible by 8 ----
    const int nwg = gridDim.x * gridDim.y * gridDim.z;
    const int bid = blockIdx.x + gridDim.x * (blockIdx.y + gridDim.y * blockIdx.z);
    const int wfl = (bid & 7) * (nwg >> 3) + (bid >> 3);   // work linear id
    const int wx  = wfl & 3;            // w-tile 0..3
    const int wy  = (wfl >> 2) & 15;    // h-tile 0..15
    const int d   = wfl >> 6;           // d-slice 0..63

    const int h0  = wy * 16;
    const int w0  = wx * 64;
    const int tid = threadIdx.x;

    // ---- band tables: 512 items (cols 32..39 pad, never read) ----
#pragma unroll
    for (int it = 0; it < 2; ++it) {
        int t = tid + it * 256;
        int n = t >> 5, k = t & 31;
        int i1 = k - n - 1;                 // W band (staged-col shift)
        int i2 = k - n;                     // H band
        float v1 = ((unsigned)i1 <= 10u) ? w11[min(max(i1, 0), 10)] : 0.f;
        float v2 = ((unsigned)i2 <= 10u) ? w11[min(max(i2, 0), 10)] : 0.f;
        WB[n][k] = (_Float16)v1;
        AH[n][k] = (_Float16)v2;
    }

    const h4* FAb = (const h4*)fields + (size_t)d * HW;

    // ---- stage fields: 32 rows x 40 col-pairs = 1280 = 5*256 exact,
    //      branchless clamped loads; garbage rows clamp into tile rows ----
    const int rmax = min(h0 + 20, 255);
#pragma unroll
    for (int it = 0; it < 5; ++it) {
        int p = tid + it * 256;
        int r = p / 40, j = p - r * 40;
        int gh = h0 - 5 + r;
        int gw = w0 - 6 + 2 * j;            // even
        bool ok = (r < 26) & ((unsigned)gh < 256u) & ((unsigned)gw < 256u);
        int idx = min(max(gh, 0), rmax) * 256 + min(max(gw, 0), 254);
        h8 va = *(const h8*)&FAb[idx];      // {X0,Y0,S0,P0, X1,Y1,S1,P1}
        if (!ok) {
            va = (h8){(_Float16)0, (_Float16)0, (_Float16)0, (_Float16)0,
                      (_Float16)0, (_Float16)0, (_Float16)0, (_Float16)0};
        }
        _Float16* pb = PB + r * 88 + j * 2;          // field stride 2816 halves
        *(h2*)(pb + 0)     = (h2){va[0], va[4]};     // X
        *(h2*)(pb + 2816)  = (h2){va[1], va[5]};     // Y
        *(h2*)(pb + 5632)  = (h2){va[2], va[6]};     // S
        *(h2*)(pb + 8448)  = (h2){va[3], va[7]};     // P
    }
    __syncthreads();   // barrier 1: staging -> W-conv reads

    const int lane = tid & 63, wid = tid >> 6;
    const int lm = lane & 15, lk = lane >> 4;
    const int col = wid * 16 + lm;                     // 0..63, wave-private block
    const int tswz = (col & 7) << 4;                   // bits 4,5 inner; bit 6 = col b0

    // ---- W-conv into registers (PB still live): 4 fields x 2 M-chunks ----
    h4 wres[8];
    {
        h8 bw = *(const h8*)((const char*)WB + lm * 80 + lk * 16);
        const char* Ab = (const char*)PB + lm * 176 + wid * 32 + lk * 16;
#pragma unroll
        for (int f = 0; f < 4; ++f) {
#pragma unroll
            for (int mc = 0; mc < 2; ++mc) {
                h8 a = *(const h8*)(Ab + f * 5632 + mc * 2816);
                f4 dv = __builtin_amdgcn_mfma_f32_16x16x32_f16(
                            a, bw, (f4){0.f, 0.f, 0.f, 0.f}, 0, 0, 0);
                wres[f * 2 + mc] = (h4){(_Float16)dv[0], (_Float16)dv[1],
                                        (_Float16)dv[2], (_Float16)dv[3]};
            }
        }
    }
    __syncthreads();   // barrier 2: all PB reads done -> safe to overwrite with TT

    // ---- write swizzled TT (aliased over PB); cols wave-private ----
    {
        char* T0 = (char*)PB;
#pragma unroll
        for (int f = 0; f < 4; ++f) {
#pragma unroll
            for (int mc = 0; mc < 2; ++mc) {
                char* dst = T0 + ((col * 64 + mc * 32 + lk * 8) ^ tswz) + f * 4096;
                *(h4*)dst = wres[f * 2 + mc];
            }
        }
    }
    // no barrier: wave reads exactly the TT cols it wrote (lgkmcnt ordered)

    // ---- H-conv MFMA (4 fields) + fused SSIM + reduction ----
    {
        h8 ah = *(const h8*)((const char*)AH + lm * 80 + lk * 16);
        const char* Tb = (const char*)PB + ((col * 64 + lk * 16) ^ tswz);
        f4 d0 = __builtin_amdgcn_mfma_f32_16x16x32_f16(ah, *(const h8*)(Tb + 0),
                    (f4){0.f,0.f,0.f,0.f}, 0, 0, 0);   // mX
        f4 d1 = __builtin_amdgcn_mfma_f32_16x16x32_f16(ah, *(const h8*)(Tb + 4096),
                    (f4){0.f,0.f,0.f,0.f}, 0, 0, 0);   // mY
        f4 d2 = __builtin_amdgcn_mfma_f32_16x16x32_f16(ah, *(const h8*)(Tb + 8192),
                    (f4){0.f,0.f,0.f,0.f}, 0, 0, 0);   // mS
        f4 d3 = __builtin_amdgcn_mfma_f32_16x16x32_f16(ah, *(const h8*)(Tb + 12288),
                    (f4){0.f,0.f,0.f,0.f}, 0, 0, 0);   // mP

        float acc = 0.f;
#pragma unroll
        for (int rg = 0; rg < 4; ++rg) {
            float mX = d0[rg], mY = d1[rg], mS = d2[rg], mP = d3[rg];
            float mx2 = mX * mX, my2 = mY * mY, mxy = mX * mY;
            float sS  = mS - mx2 - my2;      // sx2 + sy2
            float sxy = mP - mxy;
            float num = (2.f * mxy + C1v) * (2.f * sxy + C2v);
            float den = (mx2 + my2 + C1v) * (sS + C2v);
            acc += num * __builtin_amdgcn_rcpf(den + EPSv);
        }

        for (int off = 32; off; off >>= 1) acc += __shfl_down(acc, off, 64);
        if (lane == 0) wsum[wid] = acc;
        __syncthreads();
        if (tid == 0) {
            float s = wsum[0] + wsum[1] + wsum[2] + wsum[3];
            int pidx = wx + 4 * wy + 64 * d + 4096 * b;
            partials[pidx] = (double)s;
        }
    }
}

__global__ void finalize(const double* __restrict__ partials, float* __restrict__ out, int n) {
    __shared__ double sh[256];
    double s = 0.0;
    for (int i = threadIdx.x; i < n; i += 256) s += partials[i];
    sh[threadIdx.x] = s;
    __syncthreads();
    for (int stride = 128; stride; stride >>= 1) {
        if (threadIdx.x < stride) sh[threadIdx.x] += sh[threadIdx.x + stride];
        __syncthreads();
    }
    if (threadIdx.x == 0) out[0] = 1.0f - (float)(sh[0] / (double)NTOT);
}

extern "C" void kernel_launch(void* const* d_in, const int* in_sizes, int n_in,
                              void* d_out, int out_size, void* d_ws, size_t ws_size,
                              hipStream_t stream) {
    const float* x  = (const float*)d_in[0];
    const float* y  = (const float*)d_in[1];
    const float* k3 = (const float*)d_in[2];
    float* out = (float*)d_out;

    char* ws = (char*)d_ws;
    float*   w11      = (float*)ws;
    double*  partials = (double*)(ws + 64);
    char*    fields   = ws + 131136;

    init_weights<<<1, 64, 0, stream>>>(k3, w11);

    // Per-batch interleave: hw_ssim_b reads fields while L3/L2-resident
    // from dblur_b (67 MB working set/batch << 256 MB L3).
    for (int b = 0; b < 4; ++b) {
        dblur  <<<dim3(256, 2),    256, 0, stream>>>(x, y, w11, fields, b);
        hw_ssim<<<dim3(4, 16, 64), 256, 0, stream>>>(fields, w11, partials, b);
    }

    finalize<<<1, 256, 0, stream>>>(partials, out, 16384);
}

// Round 27
// 118.545 us; speedup vs baseline: 1.0890x; 1.0890x over previous
//
#include <hip/hip_runtime.h>

#define HW   (256*256)        // 65536
#define VOL  (64*HW)          // 4194304 per batch volume
#define NTOT (4ull*VOL)
#define C1v  1e-4f
#define C2v  9e-4f
#define EPSv 1e-8f

typedef float    f2 __attribute__((ext_vector_type(2)));
typedef float    f4 __attribute__((ext_vector_type(4)));
typedef _Float16 h2 __attribute__((ext_vector_type(2)));
typedef _Float16 h4 __attribute__((ext_vector_type(4)));
typedef _Float16 h8 __attribute__((ext_vector_type(8)));

// ws layout:
// [0      .. 63]       : w[11] float (1D separable weights)
// [64     .. 131135]   : partials[16384] double
// [131136 .. ]         : D-blurred fields, ONE h4 stream, 8 B/elem per batch:
//                        FA = h4{X, Y, S=x2+y2, P=xy}[VOL]

__global__ void init_weights(const float* __restrict__ k3, float* __restrict__ w) {
    int i = threadIdx.x;
    if (i < 11) {
        float s = 0.f;
        for (int t = 0; t < 121; ++t) s += k3[i * 121 + t];
        w[i] = s;   // k3 is separable: row-sum = 1D weight
    }
}

// Pass 1: D-conv of {x, y, x2+y2, xy} via scalar fp32 register rings
// (r19-proven 70us config: halves, d0 = blockIdx.y*32, cndmask zeroing).
// grid: (256, 2, nb) x 256.
__global__ __launch_bounds__(256) void dblur(
    const float* __restrict__ x, const float* __restrict__ y,
    const float* __restrict__ w11, char* __restrict__ fields, int b0)
{
    const int col = blockIdx.x * 256 + threadIdx.x;  // 0..65535 within slice
    const int d0  = blockIdx.y * 32;                 // runtime, wave-uniform
    const int bz  = blockIdx.z;
    const int b   = b0 + bz;

    float wl[11];
#pragma unroll
    for (int t = 0; t < 11; ++t) wl[t] = w11[t];

    const float* xb = x + (size_t)b * VOL;
    const float* yb = y + (size_t)b * VOL;
    h4* FA = (h4*)(fields + (size_t)bz * 8 * VOL);

    float bX[11], bY[11], bS[11], bP[11];
#pragma unroll
    for (int t = 0; t < 11; ++t) { bX[t] = 0; bY[t] = 0; bS[t] = 0; bP[t] = 0; }

#pragma unroll
    for (int s = 0; s < 42; ++s) {
        const int slot = s % 11;                    // compile-time
        int dd  = d0 - 5 + s;                       // runtime, uniform
        int ddc = min(max(dd, 0), 63);              // clamped (always-valid addr)
        bool ok = (dd >= 0) & (dd < 64);
        size_t idx = (size_t)ddc * HW + col;
        float xv = xb[idx];
        float yv = yb[idx];
        if (!ok) { xv = 0.f; yv = 0.f; }            // cndmask, no branch
        bX[slot] = xv;
        bY[slot] = yv;
        bS[slot] = xv * xv + yv * yv;
        bP[slot] = xv * yv;

        if (s >= 10) {                              // compile-time; emit d0 + s - 10
            float mX = 0, mY = 0, mS = 0, mP = 0;
#pragma unroll
            for (int t = 0; t < 11; ++t) {
                const int j = (s + 1 + t) % 11;     // compile-time; t=10 is newest
                float wt = wl[t];
                mX += wt * bX[j];
                mY += wt * bY[j];
                mS += wt * bS[j];
                mP += wt * bP[j];
            }
            size_t oi = (size_t)(d0 + s - 10) * HW + col;
            FA[oi] = (h4){(_Float16)mX, (_Float16)mY,
                          (_Float16)mS, (_Float16)mP};
        }
    }
}

// Pass 2: HW-conv via MFMA banded matmuls (verified structure, 4 fields) +
// fused SSIM map + block reduction, with bijective XCD work-swizzle (each
// XCD owns contiguous full d-slices -> halo re-reads hit same-XCD L2).
//   PB[4][32][88]; TT aliases PB, swizzle (col&7)<<4; WB/AH[16][40].
// grid: (4, 16, 64*nb) x 256.
__global__ __launch_bounds__(256) void hw_ssim(
    const char* __restrict__ fields, const float* __restrict__ w11,
    double* __restrict__ partials, int b0)
{
    __shared__ alignas(16) _Float16 PB[4 * 32 * 88];  // 22,528 B; TT (16,384 B) aliases
    __shared__ alignas(16) _Float16 WB[16][40];       //  1,280 B
    __shared__ alignas(16) _Float16 AH[16][40];       //  1,280 B
    __shared__ float wsum[4];

    // ---- bijective XCD swizzle: nwg divisible by 8 (4096 or 16384) ----
    const int nwg = gridDim.x * gridDim.y * gridDim.z;
    const int bid = blockIdx.x + gridDim.x * (blockIdx.y + gridDim.y * blockIdx.z);
    const int wfl = (bid & 7) * (nwg >> 3) + (bid >> 3);   // work linear id
    const int wx  = wfl & 3;            // w-tile 0..3
    const int wy  = (wfl >> 2) & 15;    // h-tile 0..15
    const int wz  = wfl >> 6;           // d + 64*bz

    const int d   = wz & 63;
    const int bz  = wz >> 6;
    const int h0  = wy * 16;
    const int w0  = wx * 64;
    const int tid = threadIdx.x;

    // ---- band tables: 512 items (cols 32..39 pad, never read) ----
#pragma unroll
    for (int it = 0; it < 2; ++it) {
        int t = tid + it * 256;
        int n = t >> 5, k = t & 31;
        int i1 = k - n - 1;                 // W band (staged-col shift)
        int i2 = k - n;                     // H band
        float v1 = ((unsigned)i1 <= 10u) ? w11[min(max(i1, 0), 10)] : 0.f;
        float v2 = ((unsigned)i2 <= 10u) ? w11[min(max(i2, 0), 10)] : 0.f;
        WB[n][k] = (_Float16)v1;
        AH[n][k] = (_Float16)v2;
    }

    const h4* FAb = (const h4*)(fields + (size_t)bz * 8 * VOL) + (size_t)d * HW;

    // ---- stage fields: 32 rows x 40 col-pairs = 1280 = 5*256 exact,
    //      branchless clamped loads; garbage rows clamp into tile rows ----
    const int rmax = min(h0 + 20, 255);
#pragma unroll
    for (int it = 0; it < 5; ++it) {
        int p = tid + it * 256;
        int r = p / 40, j = p - r * 40;
        int gh = h0 - 5 + r;
        int gw = w0 - 6 + 2 * j;            // even
        bool ok = (r < 26) & ((unsigned)gh < 256u) & ((unsigned)gw < 256u);
        int idx = min(max(gh, 0), rmax) * 256 + min(max(gw, 0), 254);
        h8 va = *(const h8*)&FAb[idx];      // {X0,Y0,S0,P0, X1,Y1,S1,P1}
        if (!ok) {
            va = (h8){(_Float16)0, (_Float16)0, (_Float16)0, (_Float16)0,
                      (_Float16)0, (_Float16)0, (_Float16)0, (_Float16)0};
        }
        _Float16* pb = PB + r * 88 + j * 2;          // field stride 2816 halves
        *(h2*)(pb + 0)     = (h2){va[0], va[4]};     // X
        *(h2*)(pb + 2816)  = (h2){va[1], va[5]};     // Y
        *(h2*)(pb + 5632)  = (h2){va[2], va[6]};     // S
        *(h2*)(pb + 8448)  = (h2){va[3], va[7]};     // P
    }
    __syncthreads();   // barrier 1: staging -> W-conv reads

    const int lane = tid & 63, wid = tid >> 6;
    const int lm = lane & 15, lk = lane >> 4;
    const int col = wid * 16 + lm;                     // 0..63, wave-private block
    const int tswz = (col & 7) << 4;                   // bits 4,5 inner; bit 6 = col b0

    // ---- W-conv into registers (PB still live): 4 fields x 2 M-chunks ----
    h4 wres[8];
    {
        h8 bw = *(const h8*)((const char*)WB + lm * 80 + lk * 16);
        const char* Ab = (const char*)PB + lm * 176 + wid * 32 + lk * 16;
#pragma unroll
        for (int f = 0; f < 4; ++f) {
#pragma unroll
            for (int mc = 0; mc < 2; ++mc) {
                h8 a = *(const h8*)(Ab + f * 5632 + mc * 2816);
                f4 dv = __builtin_amdgcn_mfma_f32_16x16x32_f16(
                            a, bw, (f4){0.f, 0.f, 0.f, 0.f}, 0, 0, 0);
                wres[f * 2 + mc] = (h4){(_Float16)dv[0], (_Float16)dv[1],
                                        (_Float16)dv[2], (_Float16)dv[3]};
            }
        }
    }
    __syncthreads();   // barrier 2: all PB reads done -> safe to overwrite with TT

    // ---- write swizzled TT (aliased over PB); cols wave-private ----
    {
        char* T0 = (char*)PB;
#pragma unroll
        for (int f = 0; f < 4; ++f) {
#pragma unroll
            for (int mc = 0; mc < 2; ++mc) {
                char* dst = T0 + ((col * 64 + mc * 32 + lk * 8) ^ tswz) + f * 4096;
                *(h4*)dst = wres[f * 2 + mc];
            }
        }
    }
    // no barrier: wave reads exactly the TT cols it wrote (lgkmcnt ordered)

    // ---- H-conv MFMA (4 fields) + fused SSIM + reduction ----
    {
        h8 ah = *(const h8*)((const char*)AH + lm * 80 + lk * 16);
        const char* Tb = (const char*)PB + ((col * 64 + lk * 16) ^ tswz);
        f4 d0 = __builtin_amdgcn_mfma_f32_16x16x32_f16(ah, *(const h8*)(Tb + 0),
                    (f4){0.f,0.f,0.f,0.f}, 0, 0, 0);   // mX
        f4 d1 = __builtin_amdgcn_mfma_f32_16x16x32_f16(ah, *(const h8*)(Tb + 4096),
                    (f4){0.f,0.f,0.f,0.f}, 0, 0, 0);   // mY
        f4 d2 = __builtin_amdgcn_mfma_f32_16x16x32_f16(ah, *(const h8*)(Tb + 8192),
                    (f4){0.f,0.f,0.f,0.f}, 0, 0, 0);   // mS
        f4 d3 = __builtin_amdgcn_mfma_f32_16x16x32_f16(ah, *(const h8*)(Tb + 12288),
                    (f4){0.f,0.f,0.f,0.f}, 0, 0, 0);   // mP

        float acc = 0.f;
#pragma unroll
        for (int rg = 0; rg < 4; ++rg) {
            float mX = d0[rg], mY = d1[rg], mS = d2[rg], mP = d3[rg];
            float mx2 = mX * mX, my2 = mY * mY, mxy = mX * mY;
            float sS  = mS - mx2 - my2;      // sx2 + sy2
            float sxy = mP - mxy;
            float num = (2.f * mxy + C1v) * (2.f * sxy + C2v);
            float den = (mx2 + my2 + C1v) * (sS + C2v);
            acc += num * __builtin_amdgcn_rcpf(den + EPSv);
        }

        for (int off = 32; off; off >>= 1) acc += __shfl_down(acc, off, 64);
        if (lane == 0) wsum[wid] = acc;
        __syncthreads();
        if (tid == 0) {
            float s = wsum[0] + wsum[1] + wsum[2] + wsum[3];
            int pidx = wx + 4 * wy + 64 * d + 4096 * (b0 + bz);
            partials[pidx] = (double)s;
        }
    }
}

__global__ void finalize(const double* __restrict__ partials, float* __restrict__ out, int n) {
    __shared__ double sh[256];
    double s = 0.0;
    for (int i = threadIdx.x; i < n; i += 256) s += partials[i];
    sh[threadIdx.x] = s;
    __syncthreads();
    for (int stride = 128; stride; stride >>= 1) {
        if (threadIdx.x < stride) sh[threadIdx.x] += sh[threadIdx.x + stride];
        __syncthreads();
    }
    if (threadIdx.x == 0) out[0] = 1.0f - (float)(sh[0] / (double)NTOT);
}

extern "C" void kernel_launch(void* const* d_in, const int* in_sizes, int n_in,
                              void* d_out, int out_size, void* d_ws, size_t ws_size,
                              hipStream_t stream) {
    const float* x  = (const float*)d_in[0];
    const float* y  = (const float*)d_in[1];
    const float* k3 = (const float*)d_in[2];
    float* out = (float*)d_out;

    char* ws = (char*)d_ws;
    float*   w11      = (float*)ws;
    double*  partials = (double*)(ws + 64);
    char*    fields   = ws + 131136;

    const size_t perBatch = (size_t)8 * VOL;   // h4 fields per batch (bytes)
    const bool all4 = ws_size >= 131136 + 4 * perBatch;

    init_weights<<<1, 64, 0, stream>>>(k3, w11);

    if (all4) {
        dblur  <<<dim3(256, 2, 4),  256, 0, stream>>>(x, y, w11, fields, 0);
        hw_ssim<<<dim3(4, 16, 256), 256, 0, stream>>>(fields, w11, partials, 0);
    } else {
        for (int b = 0; b < 4; ++b) {
            dblur  <<<dim3(256, 2, 1), 256, 0, stream>>>(x, y, w11, fields, b);
            hw_ssim<<<dim3(4, 16, 64), 256, 0, stream>>>(fields, w11, partials, b);
        }
    }

    finalize<<<1, 256, 0, stream>>>(partials, out, 16384);
}

// Round 28
// 115.252 us; speedup vs baseline: 1.1201x; 1.0286x over previous
//
#include <hip/hip_runtime.h>

#define HW   (256*256)        // 65536
#define VOL  (64*HW)          // 4194304 per batch volume
#define NTOT (4ull*VOL)
#define C1v  1e-4f
#define C2v  9e-4f
#define EPSv 1e-8f

typedef float    f2 __attribute__((ext_vector_type(2)));
typedef float    f4 __attribute__((ext_vector_type(4)));
typedef _Float16 h2 __attribute__((ext_vector_type(2)));
typedef _Float16 h4 __attribute__((ext_vector_type(4)));
typedef _Float16 h8 __attribute__((ext_vector_type(8)));

// ws layout:
// [0      .. 63]       : w[11] float (1D separable weights)
// [64     .. 131135]   : partials[16384] double
// [131136 .. ]         : D-blurred fields, ONE h4 stream, 8 B/elem per batch:
//                        FA = h4{X, Y, S=x2+y2, P=xy}[VOL]

__global__ void init_weights(const float* __restrict__ k3, float* __restrict__ w) {
    int i = threadIdx.x;
    if (i < 11) {
        float s = 0.f;
        for (int t = 0; t < 121; ++t) s += k3[i * 121 + t];
        w[i] = s;   // k3 is separable: row-sum = 1D weight
    }
}

// Pass 1: FULL-DEPTH D-conv of {x, y, x2+y2, xy} via scalar fp32 register
// rings. 69 steps, ALL control flow and addresses compile-time (r1-proven
// loop shape); each x/y slice read exactly once (minimal logical traffic).
// grid: (256, nb) x 256.
__global__ __launch_bounds__(256) void dblur(
    const float* __restrict__ x, const float* __restrict__ y,
    const float* __restrict__ w11, char* __restrict__ fields, int b0)
{
    const int col = blockIdx.x * 256 + threadIdx.x;  // 0..65535 within slice
    const int bz  = blockIdx.y;
    const int b   = b0 + bz;

    float wl[11];
#pragma unroll
    for (int t = 0; t < 11; ++t) wl[t] = w11[t];

    const float* xb = x + (size_t)b * VOL;
    const float* yb = y + (size_t)b * VOL;
    h4* FA = (h4*)(fields + (size_t)bz * 8 * VOL);

    float bX[11], bY[11], bS[11], bP[11];
#pragma unroll
    for (int t = 0; t < 11; ++t) { bX[t] = 0; bY[t] = 0; bS[t] = 0; bP[t] = 0; }

#pragma unroll
    for (int s = 0; s < 69; ++s) {
        const int slot = s % 11;                    // compile-time
        float xv = 0.f, yv = 0.f;
        if (s < 64) {                               // compile-time guard
            size_t idx = (size_t)s * HW + col;      // base + literal offset
            xv = xb[idx];
            yv = yb[idx];
        }
        bX[slot] = xv;
        bY[slot] = yv;
        bS[slot] = xv * xv + yv * yv;
        bP[slot] = xv * yv;

        if (s >= 5) {                               // compile-time; emit depth s-5
            // output d = s-5 uses taps dd = d-5..d+5 = s-10..s; ring holds them
            float mX = 0, mY = 0, mS = 0, mP = 0;
#pragma unroll
            for (int t = 0; t < 11; ++t) {
                const int j = (s + 1 + t) % 11;     // compile-time; oldest-first
                float wt = wl[t];
                mX += wt * bX[j];
                mY += wt * bY[j];
                mS += wt * bS[j];
                mP += wt * bP[j];
            }
            size_t oi = (size_t)(s - 5) * HW + col;
            FA[oi] = (h4){(_Float16)mX, (_Float16)mY,
                          (_Float16)mS, (_Float16)mP};
        }
    }
}

// Pass 2: HW-conv via MFMA banded matmuls (verified structure, 4 fields) +
// fused SSIM map + block reduction, with bijective XCD work-swizzle (each
// XCD owns contiguous full d-slices -> halo re-reads hit same-XCD L2).
//   PB[4][32][88]; TT aliases PB, swizzle (col&7)<<4; WB/AH[16][40].
// grid: (4, 16, 64*nb) x 256.
__global__ __launch_bounds__(256) void hw_ssim(
    const char* __restrict__ fields, const float* __restrict__ w11,
    double* __restrict__ partials, int b0)
{
    __shared__ alignas(16) _Float16 PB[4 * 32 * 88];  // 22,528 B; TT (16,384 B) aliases
    __shared__ alignas(16) _Float16 WB[16][40];       //  1,280 B
    __shared__ alignas(16) _Float16 AH[16][40];       //  1,280 B
    __shared__ float wsum[4];

    // ---- bijective XCD swizzle: nwg divisible by 8 (4096 or 16384) ----
    const int nwg = gridDim.x * gridDim.y * gridDim.z;
    const int bid = blockIdx.x + gridDim.x * (blockIdx.y + gridDim.y * blockIdx.z);
    const int wfl = (bid & 7) * (nwg >> 3) + (bid >> 3);   // work linear id
    const int wx  = wfl & 3;            // w-tile 0..3
    const int wy  = (wfl >> 2) & 15;    // h-tile 0..15
    const int wz  = wfl >> 6;           // d + 64*bz

    const int d   = wz & 63;
    const int bz  = wz >> 6;
    const int h0  = wy * 16;
    const int w0  = wx * 64;
    const int tid = threadIdx.x;

    // ---- band tables: 512 items (cols 32..39 pad, never read) ----
#pragma unroll
    for (int it = 0; it < 2; ++it) {
        int t = tid + it * 256;
        int n = t >> 5, k = t & 31;
        int i1 = k - n - 1;                 // W band (staged-col shift)
        int i2 = k - n;                     // H band
        float v1 = ((unsigned)i1 <= 10u) ? w11[min(max(i1, 0), 10)] : 0.f;
        float v2 = ((unsigned)i2 <= 10u) ? w11[min(max(i2, 0), 10)] : 0.f;
        WB[n][k] = (_Float16)v1;
        AH[n][k] = (_Float16)v2;
    }

    const h4* FAb = (const h4*)(fields + (size_t)bz * 8 * VOL) + (size_t)d * HW;

    // ---- stage fields: 32 rows x 40 col-pairs = 1280 = 5*256 exact,
    //      branchless clamped loads; garbage rows clamp into tile rows ----
    const int rmax = min(h0 + 20, 255);
#pragma unroll
    for (int it = 0; it < 5; ++it) {
        int p = tid + it * 256;
        int r = p / 40, j = p - r * 40;
        int gh = h0 - 5 + r;
        int gw = w0 - 6 + 2 * j;            // even
        bool ok = (r < 26) & ((unsigned)gh < 256u) & ((unsigned)gw < 256u);
        int idx = min(max(gh, 0), rmax) * 256 + min(max(gw, 0), 254);
        h8 va = *(const h8*)&FAb[idx];      // {X0,Y0,S0,P0, X1,Y1,S1,P1}
        if (!ok) {
            va = (h8){(_Float16)0, (_Float16)0, (_Float16)0, (_Float16)0,
                      (_Float16)0, (_Float16)0, (_Float16)0, (_Float16)0};
        }
        _Float16* pb = PB + r * 88 + j * 2;          // field stride 2816 halves
        *(h2*)(pb + 0)     = (h2){va[0], va[4]};     // X
        *(h2*)(pb + 2816)  = (h2){va[1], va[5]};     // Y
        *(h2*)(pb + 5632)  = (h2){va[2], va[6]};     // S
        *(h2*)(pb + 8448)  = (h2){va[3], va[7]};     // P
    }
    __syncthreads();   // barrier 1: staging -> W-conv reads

    const int lane = tid & 63, wid = tid >> 6;
    const int lm = lane & 15, lk = lane >> 4;
    const int col = wid * 16 + lm;                     // 0..63, wave-private block
    const int tswz = (col & 7) << 4;                   // bits 4,5 inner; bit 6 = col b0

    // ---- W-conv into registers (PB still live): 4 fields x 2 M-chunks ----
    h4 wres[8];
    {
        h8 bw = *(const h8*)((const char*)WB + lm * 80 + lk * 16);
        const char* Ab = (const char*)PB + lm * 176 + wid * 32 + lk * 16;
#pragma unroll
        for (int f = 0; f < 4; ++f) {
#pragma unroll
            for (int mc = 0; mc < 2; ++mc) {
                h8 a = *(const h8*)(Ab + f * 5632 + mc * 2816);
                f4 dv = __builtin_amdgcn_mfma_f32_16x16x32_f16(
                            a, bw, (f4){0.f, 0.f, 0.f, 0.f}, 0, 0, 0);
                wres[f * 2 + mc] = (h4){(_Float16)dv[0], (_Float16)dv[1],
                                        (_Float16)dv[2], (_Float16)dv[3]};
            }
        }
    }
    __syncthreads();   // barrier 2: all PB reads done -> safe to overwrite with TT

    // ---- write swizzled TT (aliased over PB); cols wave-private ----
    {
        char* T0 = (char*)PB;
#pragma unroll
        for (int f = 0; f < 4; ++f) {
#pragma unroll
            for (int mc = 0; mc < 2; ++mc) {
                char* dst = T0 + ((col * 64 + mc * 32 + lk * 8) ^ tswz) + f * 4096;
                *(h4*)dst = wres[f * 2 + mc];
            }
        }
    }
    // no barrier: wave reads exactly the TT cols it wrote (lgkmcnt ordered)

    // ---- H-conv MFMA (4 fields) + fused SSIM + reduction ----
    {
        h8 ah = *(const h8*)((const char*)AH + lm * 80 + lk * 16);
        const char* Tb = (const char*)PB + ((col * 64 + lk * 16) ^ tswz);
        f4 d0 = __builtin_amdgcn_mfma_f32_16x16x32_f16(ah, *(const h8*)(Tb + 0),
                    (f4){0.f,0.f,0.f,0.f}, 0, 0, 0);   // mX
        f4 d1 = __builtin_amdgcn_mfma_f32_16x16x32_f16(ah, *(const h8*)(Tb + 4096),
                    (f4){0.f,0.f,0.f,0.f}, 0, 0, 0);   // mY
        f4 d2 = __builtin_amdgcn_mfma_f32_16x16x32_f16(ah, *(const h8*)(Tb + 8192),
                    (f4){0.f,0.f,0.f,0.f}, 0, 0, 0);   // mS
        f4 d3 = __builtin_amdgcn_mfma_f32_16x16x32_f16(ah, *(const h8*)(Tb + 12288),
                    (f4){0.f,0.f,0.f,0.f}, 0, 0, 0);   // mP

        float acc = 0.f;
#pragma unroll
        for (int rg = 0; rg < 4; ++rg) {
            float mX = d0[rg], mY = d1[rg], mS = d2[rg], mP = d3[rg];
            float mx2 = mX * mX, my2 = mY * mY, mxy = mX * mY;
            float sS  = mS - mx2 - my2;      // sx2 + sy2
            float sxy = mP - mxy;
            float num = (2.f * mxy + C1v) * (2.f * sxy + C2v);
            float den = (mx2 + my2 + C1v) * (sS + C2v);
            acc += num * __builtin_amdgcn_rcpf(den + EPSv);
        }

        for (int off = 32; off; off >>= 1) acc += __shfl_down(acc, off, 64);
        if (lane == 0) wsum[wid] = acc;
        __syncthreads();
        if (tid == 0) {
            float s = wsum[0] + wsum[1] + wsum[2] + wsum[3];
            int pidx = wx + 4 * wy + 64 * d + 4096 * (b0 + bz);
            partials[pidx] = (double)s;
        }
    }
}

__global__ void finalize(const double* __restrict__ partials, float* __restrict__ out, int n) {
    __shared__ double sh[256];
    double s = 0.0;
    for (int i = threadIdx.x; i < n; i += 256) s += partials[i];
    sh[threadIdx.x] = s;
    __syncthreads();
    for (int stride = 128; stride; stride >>= 1) {
        if (threadIdx.x < stride) sh[threadIdx.x] += sh[threadIdx.x + stride];
        __syncthreads();
    }
    if (threadIdx.x == 0) out[0] = 1.0f - (float)(sh[0] / (double)NTOT);
}

extern "C" void kernel_launch(void* const* d_in, const int* in_sizes, int n_in,
                              void* d_out, int out_size, void* d_ws, size_t ws_size,
                              hipStream_t stream) {
    const float* x  = (const float*)d_in[0];
    const float* y  = (const float*)d_in[1];
    const float* k3 = (const float*)d_in[2];
    float* out = (float*)d_out;

    char* ws = (char*)d_ws;
    float*   w11      = (float*)ws;
    double*  partials = (double*)(ws + 64);
    char*    fields   = ws + 131136;

    const size_t perBatch = (size_t)8 * VOL;   // h4 fields per batch (bytes)
    const bool all4 = ws_size >= 131136 + 4 * perBatch;

    init_weights<<<1, 64, 0, stream>>>(k3, w11);

    if (all4) {
        dblur  <<<dim3(256, 4),     256, 0, stream>>>(x, y, w11, fields, 0);
        hw_ssim<<<dim3(4, 16, 256), 256, 0, stream>>>(fields, w11, partials, 0);
    } else {
        for (int b = 0; b < 4; ++b) {
            dblur  <<<dim3(256, 1),    256, 0, stream>>>(x, y, w11, fields, b);
            hw_ssim<<<dim3(4, 16, 64), 256, 0, stream>>>(fields, w11, partials, b);
        }
    }

    finalize<<<1, 256, 0, stream>>>(partials, out, 16384);
}